// Round 8
// baseline (2382.498 us; speedup 1.0000x reference)
//
#include <hip/hip_runtime.h>
#include <math.h>

// Problem constants (fixed by reference)
#define B 128
#define R 36
#define VIS 2048
#define MM 1024
#define E 512
#define ATT 512
#define D 1024
#define V 10000
#define MAXLEN 20
#define T 19          // MAXLEN - 1
#define G4 4096       // 4*D

typedef unsigned short bf16_t;
typedef __attribute__((ext_vector_type(8))) short short8;
typedef __attribute__((ext_vector_type(4))) float f32x4;
typedef __attribute__((ext_vector_type(4))) unsigned short ushort4v;

__device__ __forceinline__ bf16_t f2bf(float f) {
    unsigned u = __float_as_uint(f);
    u += 0x7fff + ((u >> 16) & 1);   // round-to-nearest-even
    return (bf16_t)(u >> 16);
}
__device__ __forceinline__ float bf2f(bf16_t b) {
    return __uint_as_float(((unsigned)b) << 16);
}
__device__ __forceinline__ float sigmoidf_(float x) { return 1.0f / (1.0f + expf(-x)); }

// Async global->LDS, 16B per lane. LDS dest = wave-uniform base + lane*16.
__device__ __forceinline__ void stage16(const bf16_t* g, bf16_t* lds_wave_base, int lane) {
#if defined(__has_builtin) && __has_builtin(__builtin_amdgcn_global_load_lds)
    __builtin_amdgcn_global_load_lds(
        (const __attribute__((address_space(1))) void*)g,
        (__attribute__((address_space(3))) void*)lds_wave_base, 16, 0, 0);
#else
    *(short8*)(lds_wave_base + lane * 8) = *(const short8*)g;
#endif
}

// ---------------------------------------------------------------------------
// 128x128-tile bf16 MFMA GEMM, m97 structure.
// MODE 0: C[m*ldc+n] = acc (+bias)               (fp32 out)
// MODE 2: vocab projection. x = n-tile (padded to 80 so XCD = x%8 is stable
//         across m-groups -> per-XCD L2-resident Wout slice), y = m-tile
//         (= timestep). Fragment/MFMA skip for fully-masked 16-row groups
//         (staging NOT skipped: r6 showed the skip costs time, not saves).
// MODE 3: bf16 out
// MODE 4: h0/c0 fused init: N=2048; n<D -> hf=v+bias[n] (+bf16 copy to C3);
//         n>=D -> C2=v+bias2[n-D]
// MODE 5: bf16 out in packed P layout for att_gates:
//         m=b*R+r, n -> dt=(n&1023)>>3, c=((n>>10)<<3)|(n&7);
//         C3[((dt*B+b)*R+r)*32 + c] = bf16(acc)
// ---------------------------------------------------------------------------
template<int MODE>
__global__ __launch_bounds__(256) void mfma_gemm_lds(
    const bf16_t* __restrict__ A, const bf16_t* __restrict__ W,
    const float* __restrict__ bias, const int* __restrict__ lengths,
    float* __restrict__ C, int M, int N, int K, int ldc,
    const float* __restrict__ bias2, float* __restrict__ C2,
    bf16_t* __restrict__ C3)
{
    __shared__ __align__(16) bf16_t As[128 * 32];
    __shared__ __align__(16) bf16_t Ws[128 * 32];
    const int tid = threadIdx.x;
    const int wave = tid >> 6, lane = tid & 63;
    const int wm = wave >> 1, wn = wave & 1;
    const int quad = lane >> 4, l16 = lane & 15;
    const int m0 = blockIdx.y * 128;
    const int n0 = blockIdx.x * 128;
    if (MODE == 2 && n0 >= N) return;        // grid.x padded to multiple of 8

    int cnt = 128;
    if constexpr (MODE == 2) {
        const int tt = blockIdx.y;           // m-tile == timestep (B==128)
        cnt = __syncthreads_count(tid < B && lengths[tid] > tt);
    }

    f32x4 acc[4][4];
    #pragma unroll
    for (int i = 0; i < 4; ++i)
        #pragma unroll
        for (int j = 0; j < 4; ++j)
            acc[i][j] = (f32x4){0.f, 0.f, 0.f, 0.f};

    for (int kk = 0; kk < K; kk += 32) {
        #pragma unroll
        for (int i = 0; i < 2; ++i) {
            int c = tid + i * 256;          // chunk 0..511
            int row = c >> 2, seg = c & 3;
            int m = m0 + row; if (m >= M) m = M - 1;
            stage16(A + (size_t)m * K + kk + seg * 8, &As[(i * 256 + wave * 64) * 8], lane);
            int n = n0 + row; if (n >= N) n = N - 1;
            stage16(W + (size_t)n * K + kk + seg * 8, &Ws[(i * 256 + wave * 64) * 8], lane);
        }
        __syncthreads();
        short8 af[4], bfr[4];
        #pragma unroll
        for (int fm = 0; fm < 4; ++fm) {
            const int rt = (MODE == 2) ? fm * 2 + wm : wm * 4 + fm;
            if (MODE != 2 || rt * 16 < cnt)
                af[fm] = *(const short8*)&As[(rt * 16 + l16) * 32 + quad * 8];
        }
        #pragma unroll
        for (int fn = 0; fn < 4; ++fn)
            bfr[fn] = *(const short8*)&Ws[(wn * 64 + fn * 16 + l16) * 32 + quad * 8];
        #pragma unroll
        for (int fm = 0; fm < 4; ++fm) {
            const int rt = (MODE == 2) ? fm * 2 + wm : wm * 4 + fm;
            if (MODE == 2 && rt * 16 >= cnt) continue;
            #pragma unroll
            for (int fn = 0; fn < 4; ++fn)
                acc[fm][fn] = __builtin_amdgcn_mfma_f32_16x16x32_bf16(
                    af[fm], bfr[fn], acc[fm][fn], 0, 0, 0);
        }
        __syncthreads();
    }

    #pragma unroll
    for (int fm = 0; fm < 4; ++fm) {
        const int rt = (MODE == 2) ? fm * 2 + wm : wm * 4 + fm;
        #pragma unroll
        for (int fn = 0; fn < 4; ++fn) {
            #pragma unroll
            for (int r = 0; r < 4; ++r) {
                int m = m0 + rt * 16 + quad * 4 + r;
                int n = n0 + wn * 64 + fn * 16 + l16;
                if (m >= M || n >= N) continue;
                float v = acc[fm][fn][r];
                if (MODE == 0) {
                    if (bias) v += bias[n];
                    C[(size_t)m * ldc + n] = v;
                } else if (MODE == 2) {
                    int t = m >> 7, b = m & 127;
                    v = (t < lengths[b]) ? (v + bias[n]) : 0.f;
                    C[((size_t)b * T + t) * V + n] = v;
                } else if (MODE == 4) {
                    if (n < D) {
                        float v2 = v + bias[n];
                        C[(size_t)m * D + n] = v2;
                        C3[(size_t)m * D + n] = f2bf(v2);
                    } else {
                        C2[(size_t)m * D + (n - D)] = v + bias2[n - D];
                    }
                } else if (MODE == 5) {
                    int b = m / R, r2 = m - b * R;
                    int dt = (n & 1023) >> 3;
                    int c = ((n >> 10) << 3) | (n & 7);
                    C3[((((size_t)dt * B + b) * R + r2) << 5) + c] = f2bf(v);
                } else {
                    ((bf16_t*)C)[(size_t)m * ldc + n] = f2bf(v);
                }
            }
        }
    }
}

// ---------------------------------------------------------------------------
// K_A: ah-tile by MFMA (mfma_ah structure), consumed IN REGISTERS into
// score partials: sc[b,r] += sum_{a in tile} relu(att_fea+ah+bias)*Ww.
// Grid (ATT/32 = 16, B/64 = 2). sc is this step's slot, pre-zeroed.
// ---------------------------------------------------------------------------
__global__ __launch_bounds__(256) void ah_scores_k(
    const bf16_t* __restrict__ h_in, const bf16_t* __restrict__ Wh_pk,
    const float* __restrict__ att_fea, const float* __restrict__ att_bias,
    const float* __restrict__ Ww, float* __restrict__ sc)
{
    __shared__ __align__(16) bf16_t Ws[32 * 1024];   // 64 KB
    const int tid = threadIdx.x;
    const int wave = tid >> 6, lane = tid & 63;
    const int quad = lane >> 4, l16 = lane & 15;
    const int a0 = blockIdx.x * 32;
    const int m0 = blockIdx.y * 64;

    const bf16_t* slab = Wh_pk + ((size_t)blockIdx.x << 15);
    #pragma unroll
    for (int i = 0; i < 16; ++i) {
        int c = i * 256 + tid;
        stage16(slab + (size_t)c * 8, &Ws[(i * 256 + wave * 64) * 8], lane);
    }
    const bf16_t* Ar = h_in + (size_t)(m0 + wave * 16 + l16) * D + quad * 8;
    f32x4 acc0 = (f32x4){0.f, 0.f, 0.f, 0.f};
    f32x4 acc1 = (f32x4){0.f, 0.f, 0.f, 0.f};
    __syncthreads();

    #pragma unroll 8
    for (int kt = 0; kt < 32; ++kt) {
        short8 af = *(const short8*)(Ar + kt * 32);
        const int cb = (kt * 4 + quad) * 32 * 8;
        short8 b0 = *(const short8*)&Ws[cb + l16 * 8];
        short8 b1 = *(const short8*)&Ws[cb + (16 + l16) * 8];
        acc0 = __builtin_amdgcn_mfma_f32_16x16x32_bf16(af, b0, acc0, 0, 0, 0);
        acc1 = __builtin_amdgcn_mfma_f32_16x16x32_bf16(af, b1, acc1, 0, 0, 0);
    }
    // acc0[rh] = ah[mb+rh][a0+l16], acc1[rh] = ah[mb+rh][a0+16+l16]
    const float ww0 = Ww[a0 + l16], ww1 = Ww[a0 + 16 + l16];
    const int mb = m0 + wave * 16 + quad * 4;
    for (int r = 0; r < R; ++r) {
        const float ab = att_bias[r];
        #pragma unroll
        for (int rh = 0; rh < 4; ++rh) {
            const float* af = att_fea + ((size_t)(mb + rh) * R + r) * ATT + a0;
            float s = fmaxf(af[l16] + acc0[rh] + ab, 0.f) * ww0
                    + fmaxf(af[16 + l16] + acc1[rh] + ab, 0.f) * ww1;
            s += __shfl_xor(s, 1); s += __shfl_xor(s, 2);
            s += __shfl_xor(s, 4); s += __shfl_xor(s, 8);
            if (l16 == 0) atomicAdd(&sc[(size_t)(mb + rh) * R + r], s);
        }
    }
}

// ---------------------------------------------------------------------------
// K_B: softmax(sc) -> alpha (registers, 4 lanes/row) -> P_pk contraction
// (+wordsW) -> part_s LDS -> single barrier -> MFMA h-GEMM + LSTM pointwise.
// Whh slab staging is issued FIRST and overlaps softmax+contraction.
// Grid (128 d-tiles, 2 m-tiles). One barrier per step.
// ---------------------------------------------------------------------------
__global__ __launch_bounds__(256) void att_gates_k(
    const bf16_t* __restrict__ h_in, const bf16_t* __restrict__ Whh_pk,
    const float* __restrict__ sc, const bf16_t* __restrict__ P_pk,
    const float* __restrict__ wordsW_t,
    const float* __restrict__ bih, const float* __restrict__ bhh,
    const int* __restrict__ lengths,
    float* __restrict__ c_st, float* __restrict__ h_f32,
    bf16_t* __restrict__ h_out, bf16_t* __restrict__ hseq, int t)
{
    __shared__ __align__(16) bf16_t Ws[32 * 1024];   // 64 KB
    __shared__ float part_s[64 * 36];                // stride 36: 2-way banks max
    const int tid = threadIdx.x;
    const int wave = tid >> 6, lane = tid & 63;
    const int quad = lane >> 4, l16 = lane & 15;
    const int dt = blockIdx.x, d0 = dt * 8;
    const int m0 = blockIdx.y * 64;
    const int gsel_ = l16 >> 3, dr = l16 & 7;

    // ---- issue Whh slab staging (async; overlaps the phases below) ----
    const bf16_t* slab = Whh_pk + ((size_t)dt << 15);
    #pragma unroll
    for (int i = 0; i < 16; ++i) {
        int c = i * 256 + tid;
        stage16(slab + (size_t)c * 8, &Ws[(i * 256 + wave * 64) * 8], lane);
    }

    // ---- softmax over R=36 (4 lanes per m-row, 9 r's each) ----
    const int m_loc = tid >> 2, sub = tid & 3;
    float av[9];
    if (t > 0) {
        const float* sr = sc + (size_t)(m0 + m_loc) * R + sub * 9;
        float mx = -INFINITY;
        #pragma unroll
        for (int j = 0; j < 9; ++j) { av[j] = sr[j]; mx = fmaxf(mx, av[j]); }
        mx = fmaxf(mx, __shfl_xor(mx, 1));
        mx = fmaxf(mx, __shfl_xor(mx, 2));
        float sm = 0.f;
        #pragma unroll
        for (int j = 0; j < 9; ++j) { av[j] = expf(av[j] - mx); sm += av[j]; }
        sm += __shfl_xor(sm, 1); sm += __shfl_xor(sm, 2);
        float inv = 1.f / sm;
        #pragma unroll
        for (int j = 0; j < 9; ++j) av[j] *= inv;
    }

    // ---- P contraction: thread (m_loc, cg) does 8 cols, coalesced 16B/r ----
    const int cg = sub;
    float a8[8];
    #pragma unroll
    for (int j = 0; j < 8; ++j) a8[j] = 0.f;
    const bf16_t* Pb = P_pk + ((((size_t)dt * B + (m0 + m_loc)) * R) << 5) + cg * 8;
    const int lgbase = lane & ~3;
    #pragma unroll
    for (int r = 0; r < R; ++r) {
        float al = (t == 0) ? (1.0f / R) : __shfl(av[r % 9], lgbase + r / 9);
        short8 p = *(const short8*)(Pb + r * 32);
        #pragma unroll
        for (int j = 0; j < 8; ++j)
            a8[j] = fmaf(al, bf2f((bf16_t)p[j]), a8[j]);
    }
    {   // + wordsW (cols cg*1024 + d0 .. +8 are contiguous fp32)
        const float* wsl = wordsW_t + (size_t)(m0 + m_loc) * G4 + cg * 1024 + d0;
        float4 w0 = *(const float4*)wsl;
        float4 w1 = *(const float4*)(wsl + 4);
        float* ps = &part_s[m_loc * 36 + cg * 8];
        ps[0] = a8[0] + w0.x; ps[1] = a8[1] + w0.y;
        ps[2] = a8[2] + w0.z; ps[3] = a8[3] + w0.w;
        ps[4] = a8[4] + w1.x; ps[5] = a8[5] + w1.y;
        ps[6] = a8[6] + w1.z; ps[7] = a8[7] + w1.w;
    }

    const bf16_t* Ar = h_in + (size_t)(m0 + wave * 16 + l16) * D + quad * 8;
    f32x4 acc0 = (f32x4){0.f, 0.f, 0.f, 0.f};
    f32x4 acc1 = (f32x4){0.f, 0.f, 0.f, 0.f};
    __syncthreads();    // drains staging vmcnt + orders part_s

    #pragma unroll 8
    for (int kt = 0; kt < 32; ++kt) {
        short8 af = *(const short8*)(Ar + kt * 32);
        const int cb = (kt * 4 + quad) * 32 * 8;
        short8 b0 = *(const short8*)&Ws[cb + l16 * 8];
        short8 b1 = *(const short8*)&Ws[cb + (16 + l16) * 8];
        acc0 = __builtin_amdgcn_mfma_f32_16x16x32_bf16(af, b0, acc0, 0, 0, 0);
        acc1 = __builtin_amdgcn_mfma_f32_16x16x32_bf16(af, b1, acc1, 0, 0, 0);
    }

    const int d = d0 + dr;
    const int col0 = gsel_ * D + d;
    const int col1 = (2 + gsel_) * D + d;
    const float bia0 = bih[col0] + bhh[col0];
    const float bia1 = bih[col1] + bhh[col1];

    #pragma unroll
    for (int r = 0; r < 4; ++r) {
        int ml = wave * 16 + quad * 4 + r;
        int m = m0 + ml;
        float v0 = acc0[r] + bia0 + part_s[ml * 36 + gsel_ * 8 + dr];
        float v1 = acc1[r] + bia1 + part_s[ml * 36 + 16 + gsel_ * 8 + dr];
        float w0 = __shfl_xor(v0, 8);
        float w1 = __shfl_xor(v1, 8);
        float iv, fv, gv, ov;
        if (gsel_ == 0) { iv = v0; gv = v1; fv = w0; ov = w1; }
        else            { fv = v0; ov = v1; iv = w0; gv = w1; }
        float ig = sigmoidf_(iv), fg = sigmoidf_(fv);
        float gg = tanhf(gv),     og = sigmoidf_(ov);
        size_t off = (size_t)m * D + d;
        if (gsel_ == 0) {
            float c_old = c_st[off];
            float h_old = h_f32[off];
            float cn = fmaf(fg, c_old, ig * gg);
            float hn = og * tanhf(cn);
            bool msk = t < lengths[m];
            float cv = msk ? cn : c_old;
            float hv = msk ? hn : h_old;
            c_st[off] = cv;
            h_f32[off] = hv;
            bf16_t hb = f2bf(hv);
            h_out[off] = hb;
            hseq[((size_t)t * B + m) * D + d] = hb;
        }
    }
}

// ---------------------------------------------------------------------------
// One-shot Whh re-pack: per d-tile a contiguous 64KB slab in EXACTLY the
// LDS layout att_gates wants (chunk c = qk*32+row; row = gathered gate-row).
// ---------------------------------------------------------------------------
__global__ __launch_bounds__(256) void whh_pack_k(
    const bf16_t* __restrict__ Whh, bf16_t* __restrict__ pk)
{
    int idx = blockIdx.x * 256 + threadIdx.x;    // 128*4096 chunks
    int dt = idx >> 12, c = idx & 4095;
    int row = c & 31, qk = c >> 5;
    int rv = (row >> 3) * D + dt * 8 + (row & 7);
    *(short8*)(pk + ((size_t)dt << 15) + (size_t)c * 8) =
        *(const short8*)(Whh + (size_t)rv * D + qk * 8);
}

// One-shot Wh re-pack for ah_scores: a-tile at owns rows at*32..+32.
__global__ __launch_bounds__(256) void wh_pack_k(
    const bf16_t* __restrict__ Wh, bf16_t* __restrict__ pk)
{
    int idx = blockIdx.x * 256 + threadIdx.x;    // 16*4096 chunks
    int at = idx >> 12, c = idx & 4095;
    int row = c & 31, qk = c >> 5;
    *(short8*)(pk + ((size_t)at << 15) + (size_t)c * 8) =
        *(const short8*)(Wh + (size_t)(at * 32 + row) * D + qk * 8);
}

// ---------------------------------------------------------------------------
// Fused bf16 cast: all 10 weight/activation casts in ONE dispatch.
// ---------------------------------------------------------------------------
struct CastSeg { const float* s; bf16_t* d; int cols; int ld; int total4; int blk0; };
struct Cast10 { CastSeg g[10]; };

__global__ __launch_bounds__(256) void fused_cast_k(Cast10 a)
{
    const int bx = blockIdx.x;
    CastSeg sg = a.g[0];
    #pragma unroll
    for (int j = 1; j < 10; ++j) if (bx >= a.g[j].blk0) sg = a.g[j];
    int idx = (bx - sg.blk0) * 256 + threadIdx.x;
    if (idx >= sg.total4) return;
    int cq = sg.cols >> 2;
    int r = idx / cq, c4 = (idx - r * cq) * 4;
    float4 v = *(const float4*)(sg.s + (size_t)r * sg.ld + c4);
    ushort4v o = { f2bf(v.x), f2bf(v.y), f2bf(v.z), f2bf(v.w) };
    *(ushort4v*)(sg.d + (size_t)r * sg.cols + c4) = o;
}

// words_bf[(t*B+b)*E + :] = bf16(embed_W[captions[b][t]][:])
__global__ __launch_bounds__(128) void embed_k(
    const int* __restrict__ captions, const float* __restrict__ embed_W,
    bf16_t* __restrict__ words_bf)
{
    int bt = blockIdx.x;
    int b = bt / T, t = bt - b * T;
    int tok = captions[b * MAXLEN + t];
    int i = threadIdx.x * 4;
    float4 v = *(const float4*)(embed_W + (size_t)tok * E + i);
    ushort4v o = { f2bf(v.x), f2bf(v.y), f2bf(v.z), f2bf(v.w) };
    *(ushort4v*)(words_bf + ((size_t)t * B + b) * E + i) = o;
}

extern "C" void kernel_launch(void* const* d_in, const int* in_sizes, int n_in,
                              void* d_out, int out_size, void* d_ws, size_t ws_size,
                              hipStream_t stream) {
    const float* visual   = (const float*)d_in[0];
    const float* joint    = (const float*)d_in[1];
    const int*   captions = (const int*)d_in[2];
    const int*   lengths  = (const int*)d_in[3];
    const float* embed_W  = (const float*)d_in[5];
    const float* Wih      = (const float*)d_in[6];
    const float* bih      = (const float*)d_in[7];
    const float* Whh      = (const float*)d_in[8];
    const float* bhh      = (const float*)d_in[9];
    const float* W_init_h = (const float*)d_in[10];
    const float* b_init_h = (const float*)d_in[11];
    const float* W_init_c = (const float*)d_in[12];
    const float* b_init_c = (const float*)d_in[13];
    const float* Wv       = (const float*)d_in[14];
    const float* Wh       = (const float*)d_in[15];
    const float* att_bias = (const float*)d_in[16];
    const float* Ww       = (const float*)d_in[17];
    const float* Wout     = (const float*)d_in[18];
    const float* bout     = (const float*)d_in[19];
    float* out = (float*)d_out;

    // ---- workspace carve-up ----
    char* cur = (char*)d_ws;
    auto alloc = [&](size_t bytes) { char* p = cur; cur += (bytes + 15) & ~size_t(15); return p; };
    float*  att_fea  = (float*)alloc((size_t)B * R * ATT * 4);       // 9.4 MB
    float*  wordsW   = (float*)alloc((size_t)T * B * G4 * 4);        // 39.8 MB
    float*  hf       = (float*)alloc((size_t)B * D * 4);
    float*  c_st     = (float*)alloc((size_t)B * D * 4);
    float*  sc_t     = (float*)alloc((size_t)T * B * R * 4);         // 350 KB
    bf16_t* words_bf = (bf16_t*)alloc((size_t)T * B * E * 2);
    bf16_t* h_ping0  = (bf16_t*)alloc((size_t)B * D * 2);
    bf16_t* h_ping1  = (bf16_t*)alloc((size_t)B * D * 2);
    bf16_t* hseq_bf  = (bf16_t*)alloc((size_t)T * B * D * 2);        // 5 MB
    bf16_t* P_pk     = (bf16_t*)alloc((size_t)B * R * G4 * 2);       // 37.7 MB packed
    bf16_t* visual_bf= (bf16_t*)alloc((size_t)B * R * VIS * 2);      // 18.9 MB
    bf16_t* Wv_bf    = (bf16_t*)alloc((size_t)ATT * VIS * 2);
    bf16_t* Wh_bf    = (bf16_t*)alloc((size_t)ATT * D * 2);
    bf16_t* Wh_pk    = (bf16_t*)alloc((size_t)ATT * D * 2);          // 1 MB packed
    bf16_t* Whh_bf   = (bf16_t*)alloc((size_t)G4 * D * 2);
    bf16_t* Whh_pk   = (bf16_t*)alloc((size_t)G4 * D * 2);           // 8 MB packed
    bf16_t* Wih_v_bf = (bf16_t*)alloc((size_t)G4 * VIS * 2);
    bf16_t* Wih_w_bf = (bf16_t*)alloc((size_t)G4 * E * 2);
    bf16_t* Wout_bf  = (bf16_t*)alloc((size_t)V * D * 2);
    bf16_t* joint_bf = (bf16_t*)alloc((size_t)B * MM * 2);
    bf16_t* Winit_bf = (bf16_t*)alloc((size_t)2 * D * MM * 2);       // stacked Wh0;Wc0

    // ---- single fused cast dispatch ----
    Cast10 ca;
    int cum = 0;
    auto seg = [&](int i, const float* s, bf16_t* d, int rows, int cols, int ld) {
        int t4 = rows * (cols >> 2);
        ca.g[i] = { s, d, cols, ld, t4, cum };
        cum += (t4 + 255) / 256;
    };
    seg(0, visual, visual_bf, 1, B * R * VIS, B * R * VIS);
    seg(1, Wv,  Wv_bf,  ATT, VIS, VIS);
    seg(2, Wh,  Wh_bf,  ATT, D, D);
    seg(3, Whh, Whh_bf, G4, D, D);
    seg(4, Wih, Wih_v_bf, G4, VIS, VIS + E);
    seg(5, Wih + VIS, Wih_w_bf, G4, E, VIS + E);
    seg(6, Wout, Wout_bf, V, D, D);
    seg(7, joint, joint_bf, 1, B * MM, B * MM);
    seg(8, W_init_h, Winit_bf, 1, D * MM, D * MM);
    seg(9, W_init_c, Winit_bf + (size_t)D * MM, 1, D * MM, D * MM);
    fused_cast_k<<<cum, 256, 0, stream>>>(ca);

    whh_pack_k<<<(128 * 4096) / 256, 256, 0, stream>>>(Whh_bf, Whh_pk);
    wh_pack_k<<<(16 * 4096) / 256, 256, 0, stream>>>(Wh_bf, Wh_pk);
    embed_k<<<B * T, 128, 0, stream>>>(captions, embed_W, words_bf);
    hipMemsetAsync(sc_t, 0, (size_t)T * B * R * 4, stream);

    // h0/c0 fused init (MODE 4): one GEMM, bf16 h0 written in epilogue
    mfma_gemm_lds<4><<<dim3(16, 1), 256, 0, stream>>>(
        joint_bf, Winit_bf, b_init_h, nullptr, hf, B, 2 * D, MM, D,
        b_init_c, c_st, h_ping0);

    // att_fea = visual @ Wv^T (fp32 out)
    mfma_gemm_lds<0><<<dim3(ATT / 128, (B * R) / 128), 256, 0, stream>>>(
        visual_bf, Wv_bf, nullptr, nullptr, att_fea, B * R, ATT, VIS, ATT,
        nullptr, nullptr, nullptr);

    // wordsW = words @ Wih_w^T (all steps)
    mfma_gemm_lds<0><<<dim3(G4 / 128, (T * B) / 128), 256, 0, stream>>>(
        words_bf, Wih_w_bf, nullptr, nullptr, wordsW, T * B, G4, E, G4,
        nullptr, nullptr, nullptr);

    // P = visual @ Wih_v^T, written directly in the packed att_gates layout
    mfma_gemm_lds<5><<<dim3(G4 / 128, (B * R) / 128), 256, 0, stream>>>(
        visual_bf, Wih_v_bf, nullptr, nullptr, nullptr, B * R, G4, VIS, G4,
        nullptr, nullptr, P_pk);

    // ---- recurrence: 2 kernels per step (1 at t=0) ----
    bf16_t* h_buf[2] = { h_ping0, h_ping1 };
    for (int t = 0; t < T; ++t) {
        float* sct = sc_t + (size_t)t * B * R;
        if (t > 0)
            ah_scores_k<<<dim3(ATT / 32, B / 64), 256, 0, stream>>>(
                h_buf[t & 1], Wh_pk, att_fea, att_bias, Ww, sct);
        att_gates_k<<<dim3(D / 8, B / 64), 256, 0, stream>>>(
            h_buf[t & 1], Whh_pk, sct, P_pk, wordsW + (size_t)t * B * G4,
            bih, bhh, lengths, c_st, hf, h_buf[(t + 1) & 1], hseq_bf, t);
    }

    // ---- deferred vocab projection (x = n-tile padded to 80, y = m-tile) ----
    mfma_gemm_lds<2><<<dim3(80, (T * B) / 128), 256, 0, stream>>>(
        hseq_bf, Wout_bf, bout, lengths, out, T * B, V, D, V,
        nullptr, nullptr, nullptr);
}